// Round 1
// baseline (147.224 us; speedup 1.0000x reference)
//
#include <hip/hip_runtime.h>
#include <math.h>

#define NSTEPS 18
#define NS 128      // N_CES*B
#define CHW 12288   // 3*64*64
#define HW 4096     // 64*64
#define NCLS 1000

struct StepC { float c_skip, c_out, c_in, inv_t, ce, two_dt, nc, pad; };
struct Steps { StepC s[NSTEPS]; float t0; };

// ---------------- Sampler: one block per sample, full state in LDS ----------------
__global__ __launch_bounds__(512)
void sampler_kernel(const float* __restrict__ x, const float* __restrict__ latents,
                    const float* __restrict__ noise, const float* __restrict__ Wn_g,
                    const float* __restrict__ bn_g, float* __restrict__ Aout, Steps S)
{
    __shared__ float xs[CHW];     // [3][64][64]
    __shared__ float Wn[81];
    __shared__ float bn[3];
    const int tid = threadIdx.x;
    const int n = blockIdx.x;
    const float* lat = latents + (size_t)n * CHW;
    const float* xin = x + (size_t)(n & 63) * CHW;

    if (tid < 81) Wn[tid] = Wn_g[tid];
    if (tid < 3)  bn[tid] = bn_g[tid];

    // stage x0 = latents * t0
    const float t0 = S.t0;
    for (int i = tid; i < CHW; i += 512) xs[i] = lat[i] * t0;

    const int r = tid >> 3;        // row 0..63
    const int sc = tid & 7;        // strip 0..7
    const int cbase = sc << 3;     // col base (8-wide strip)

    // preload mu = 2*x - 1 for this thread's 24 outputs
    float mu[3][8];
    #pragma unroll
    for (int co = 0; co < 3; ++co) {
        const float* mb = xin + co * HW + r * 64 + cbase;
        float4 m0 = *reinterpret_cast<const float4*>(mb);
        float4 m1 = *reinterpret_cast<const float4*>(mb + 4);
        mu[co][0] = 2.f*m0.x - 1.f; mu[co][1] = 2.f*m0.y - 1.f;
        mu[co][2] = 2.f*m0.z - 1.f; mu[co][3] = 2.f*m0.w - 1.f;
        mu[co][4] = 2.f*m1.x - 1.f; mu[co][5] = 2.f*m1.y - 1.f;
        mu[co][6] = 2.f*m1.z - 1.f; mu[co][7] = 2.f*m1.w - 1.f;
    }
    __syncthreads();

    for (int step = 0; step < NSTEPS; ++step) {
        const StepC c = S.s[step];
        float acc[3][8];
        #pragma unroll
        for (int co = 0; co < 3; ++co)
            #pragma unroll
            for (int j = 0; j < 8; ++j) acc[co][j] = 0.f;
        float xsave[3][8];

        #pragma unroll
        for (int ci = 0; ci < 3; ++ci) {
            float in[3][10];
            #pragma unroll
            for (int dh = 0; dh < 3; ++dh) {
                const int rr = r + dh - 1;
                if (rr >= 0 && rr < 64) {
                    const float* base = &xs[ci * HW + rr * 64 + cbase];
                    float4 a = *reinterpret_cast<const float4*>(base);
                    float4 b = *reinterpret_cast<const float4*>(base + 4);
                    in[dh][1] = a.x; in[dh][2] = a.y; in[dh][3] = a.z; in[dh][4] = a.w;
                    in[dh][5] = b.x; in[dh][6] = b.y; in[dh][7] = b.z; in[dh][8] = b.w;
                    in[dh][0] = (cbase > 0)  ? base[-1] : 0.f;
                    in[dh][9] = (cbase < 56) ? base[8]  : 0.f;
                } else {
                    #pragma unroll
                    for (int q = 0; q < 10; ++q) in[dh][q] = 0.f;
                }
            }
            #pragma unroll
            for (int j = 0; j < 8; ++j) xsave[ci][j] = in[1][j + 1];

            #pragma unroll
            for (int co = 0; co < 3; ++co)
                #pragma unroll
                for (int dh = 0; dh < 3; ++dh)
                    #pragma unroll
                    for (int dw = 0; dw < 3; ++dw) {
                        const float w = Wn[((co * 3 + ci) * 3 + dh) * 3 + dw];
                        #pragma unroll
                        for (int j = 0; j < 8; ++j)
                            acc[co][j] = fmaf(w, in[dh][j + dw], acc[co][j]);
                    }
        }

        // EDM update
        const float* nz = noise + ((size_t)(step * NS + n)) * CHW;
        float xnew[3][8];
        #pragma unroll
        for (int co = 0; co < 3; ++co) {
            const float* nb = nz + co * HW + r * 64 + cbase;
            float4 e0 = *reinterpret_cast<const float4*>(nb);
            float4 e1 = *reinterpret_cast<const float4*>(nb + 4);
            float eps[8] = {e0.x, e0.y, e0.z, e0.w, e1.x, e1.y, e1.z, e1.w};
            #pragma unroll
            for (int j = 0; j < 8; ++j) {
                const float xc = xsave[co][j];
                const float f = fmaf(c.c_in, acc[co][j], bn[co]);
                const float den = c.c_skip * xc + c.c_out * f;
                const float dx = (den - xc) * c.inv_t + c.ce * (mu[co][j] - xc);
                xnew[co][j] = xc + c.two_dt * dx + c.nc * eps[j];
            }
        }
        __syncthreads();
        #pragma unroll
        for (int co = 0; co < 3; ++co) {
            float* base = &xs[co * HW + r * 64 + cbase];
            *reinterpret_cast<float4*>(base)     = make_float4(xnew[co][0], xnew[co][1], xnew[co][2], xnew[co][3]);
            *reinterpret_cast<float4*>(base + 4) = make_float4(xnew[co][4], xnew[co][5], xnew[co][6], xnew[co][7]);
        }
        __syncthreads();
    }

    // A = (x_final + 1)/2
    float* Ao = Aout + (size_t)n * CHW;
    for (int i = tid; i < CHW; i += 512) Ao[i] = (xs[i] + 1.f) * 0.5f;
}

// ---------------- GEMM: C[128][1000] partials, K split across blocks ----------------
__global__ __launch_bounds__(256)
void gemm_kernel(const float* __restrict__ A, const float* __restrict__ Wc,
                 float* __restrict__ part, int bkc)
{
    __shared__ float As[16][132];   // [k][row], padded
    __shared__ float Ws[16][64];    // [k][col]
    const int tid = threadIdx.x;
    const int ct = blockIdx.x & 15;      // col tile (16 x 64 = 1024 >= 1000)
    const int kc = blockIdx.x >> 4;      // k chunk
    const int c0 = ct << 6;
    const int k0 = kc * bkc;
    const int rg = tid >> 4;             // 0..15 -> rows rg*8..+8
    const int cg = tid & 15;             // 0..15 -> cols cg*4..+4

    float acc[8][4];
    #pragma unroll
    for (int i = 0; i < 8; ++i)
        #pragma unroll
        for (int j = 0; j < 4; ++j) acc[i][j] = 0.f;

    for (int kk = 0; kk < bkc; kk += 16) {
        #pragma unroll
        for (int p = 0; p < 2; ++p) {
            const int u = tid + p * 256;
            const int row = u >> 2;
            const int ks4 = (u & 3) << 2;
            float4 v = *reinterpret_cast<const float4*>(A + (size_t)row * CHW + k0 + kk + ks4);
            As[ks4 + 0][row] = v.x; As[ks4 + 1][row] = v.y;
            As[ks4 + 2][row] = v.z; As[ks4 + 3][row] = v.w;
        }
        {
            const int wr = tid >> 4;
            const int wcc = (tid & 15) << 2;
            const int col = c0 + wcc;
            float4 v = make_float4(0.f, 0.f, 0.f, 0.f);
            if (col < NCLS)
                v = *reinterpret_cast<const float4*>(Wc + (size_t)(k0 + kk + wr) * NCLS + col);
            *reinterpret_cast<float4*>(&Ws[wr][wcc]) = v;
        }
        __syncthreads();
        #pragma unroll
        for (int k = 0; k < 16; ++k) {
            const float4 a0 = *reinterpret_cast<const float4*>(&As[k][rg * 8]);
            const float4 a1 = *reinterpret_cast<const float4*>(&As[k][rg * 8 + 4]);
            const float4 b  = *reinterpret_cast<const float4*>(&Ws[k][cg * 4]);
            const float av[8] = {a0.x, a0.y, a0.z, a0.w, a1.x, a1.y, a1.z, a1.w};
            const float bv[4] = {b.x, b.y, b.z, b.w};
            #pragma unroll
            for (int i = 0; i < 8; ++i)
                #pragma unroll
                for (int j = 0; j < 4; ++j)
                    acc[i][j] = fmaf(av[i], bv[j], acc[i][j]);
        }
        __syncthreads();
    }

    float* pp = part + (size_t)kc * NS * NCLS;
    #pragma unroll
    for (int i = 0; i < 8; ++i) {
        const int row = rg * 8 + i;
        const int col = c0 + (cg << 2);
        if (col < NCLS)
            *reinterpret_cast<float4*>(pp + (size_t)row * NCLS + col) =
                make_float4(acc[i][0], acc[i][1], acc[i][2], acc[i][3]);
    }
}

// ---------------- Reduce partials + bias + logsumexp over the 2 CEs ----------------
__global__ __launch_bounds__(256)
void lse_kernel(const float* __restrict__ part, const float* __restrict__ bcls,
                float* __restrict__ out, int ks)
{
    const int i = blockIdx.x * 256 + threadIdx.x;
    if (i >= 64 * NCLS) return;
    const int b = i / NCLS;
    const int k = i - b * NCLS;
    float l0 = bcls[k], l1 = bcls[k];
    for (int kc = 0; kc < ks; ++kc) {
        l0 += part[(size_t)kc * NS * NCLS + (size_t)b * NCLS + k];
        l1 += part[(size_t)kc * NS * NCLS + (size_t)(b + 64) * NCLS + k];
    }
    const float m = fmaxf(l0, l1);
    out[i] = m + logf(expf(l0 - m) + expf(l1 - m)) - 0.69314718055994530942f;
}

extern "C" void kernel_launch(void* const* d_in, const int* in_sizes, int n_in,
                              void* d_out, int out_size, void* d_ws, size_t ws_size,
                              hipStream_t stream) {
    const float* x       = (const float*)d_in[0];
    const float* latents = (const float*)d_in[1];
    const float* noise   = (const float*)d_in[2];
    const float* W_net   = (const float*)d_in[3];
    const float* b_net   = (const float*)d_in[4];
    const float* W_cls   = (const float*)d_in[5];
    const float* b_cls   = (const float*)d_in[6];
    float* out = (float*)d_out;
    float* ws  = (float*)d_ws;

    float* Amat = ws;                       // 128*12288 floats
    float* part = ws + (size_t)NS * CHW;    // KS*128*1000 floats

    // Karras sigma schedule in float64 (matches numpy), cast to f32
    Steps S;
    const double smin = pow(0.002, 1.0 / 7.0), smax = pow(80.0, 1.0 / 7.0);
    float tsf[NSTEPS + 1];
    for (int i = 0; i < NSTEPS; ++i) {
        double v = smax + (double)i / (double)(NSTEPS - 1) * (smin - smax);
        tsf[i] = (float)pow(v, 7.0);
    }
    tsf[NSTEPS] = 0.f;
    S.t0 = tsf[0];
    for (int i = 0; i < NSTEPS; ++i) {
        const float t = tsf[i], tn = tsf[i + 1];
        const float s2 = t * t, denom = s2 + 0.25f;
        StepC c;
        c.c_skip = 0.25f / denom;
        c.c_out  = t * 0.5f / sqrtf(denom);
        c.c_in   = 1.0f / sqrtf(denom);
        c.inv_t  = 1.0f / t;
        c.ce     = t / (0.04f + s2);
        const float dt = t - tn;
        c.two_dt = 2.f * dt;
        c.nc     = sqrtf(2.f * t * dt);
        c.pad    = 0.f;
        S.s[i] = c;
    }

    // pick largest K-split that fits in workspace
    int KSr = 32;
    while (KSr > 1 && (size_t)(NS * CHW + (size_t)KSr * NS * NCLS) * 4 > ws_size) KSr >>= 1;
    const int bkc = CHW / KSr;

    sampler_kernel<<<NS, 512, 0, stream>>>(x, latents, noise, W_net, b_net, Amat, S);
    gemm_kernel<<<16 * KSr, 256, 0, stream>>>(Amat, W_cls, part, bkc);
    lse_kernel<<<(64 * NCLS + 255) / 256, 256, 0, stream>>>(part, b_cls, out, KSr);
}